// Round 1
// baseline (701.242 us; speedup 1.0000x reference)
//
#include <hip/hip_runtime.h>
#include <hip/hip_bf16.h>

// Problem constants (from reference): N=50000 nodes, IN=256, H=8 heads, D=32,
// HD=256, E=800000 edges. N and E derived from in_sizes at launch.

#define GEMM_TM 128
#define GEMM_TN 128
#define GEMM_BK 32

// Fused QKV projection: out[n,j] = sum_k h[n,k]*W[j,k] + b[j]
// grid.x = ceil(N/128), grid.y = 6 (2 col-tiles per matrix x 3 matrices)
__global__ __launch_bounds__(256) void qkv_gemm(
    const float* __restrict__ h,
    const float* __restrict__ Wq, const float* __restrict__ bq,
    const float* __restrict__ Wk, const float* __restrict__ bk,
    const float* __restrict__ Wv, const float* __restrict__ bv,
    float* __restrict__ Q, float* __restrict__ K, float* __restrict__ V,
    int N)
{
    __shared__ float As[GEMM_BK][GEMM_TM + 4];  // [k][row], k-major for b128 frag reads
    __shared__ float Bs[GEMM_BK][GEMM_TN + 4];

    const int mbase = blockIdx.x * GEMM_TM;
    const int ctile = blockIdx.y;          // 0..5
    const int mat = ctile >> 1;            // 0:Q 1:K 2:V
    const int colbase = (ctile & 1) * GEMM_TN;  // 0 or 128 within matrix

    const float* W    = (mat == 0) ? Wq : (mat == 1) ? Wk : Wv;
    const float* bias = (mat == 0) ? bq : (mat == 1) ? bk : bv;
    float* Out        = (mat == 0) ? Q  : (mat == 1) ? K  : V;

    const int tid = threadIdx.x;
    const int tx = tid & 15;       // col group
    const int ty = tid >> 4;       // row group

    float acc[8][8];
#pragma unroll
    for (int i = 0; i < 8; i++)
#pragma unroll
        for (int j = 0; j < 8; j++) acc[i][j] = 0.f;

    for (int kk = 0; kk < 256; kk += GEMM_BK) {
        // Stage A tile: 128 rows x 32 k  (1024 float4, 4 per thread)
#pragma unroll
        for (int i = 0; i < 4; i++) {
            int idx = tid + i * 256;       // 0..1023
            int row = idx >> 3;            // 0..127
            int c4  = idx & 7;             // 0..7
            int grow = mbase + row;
            float4 a = make_float4(0.f, 0.f, 0.f, 0.f);
            if (grow < N) a = *(const float4*)&h[(size_t)grow * 256 + kk + c4 * 4];
            int kc = c4 * 4;
            As[kc + 0][row] = a.x; As[kc + 1][row] = a.y;
            As[kc + 2][row] = a.z; As[kc + 3][row] = a.w;
        }
        // Stage B tile: 128 feats x 32 k
#pragma unroll
        for (int i = 0; i < 4; i++) {
            int idx = tid + i * 256;
            int row = idx >> 3;
            int c4  = idx & 7;
            float4 b = *(const float4*)&W[(size_t)(colbase + row) * 256 + kk + c4 * 4];
            int kc = c4 * 4;
            Bs[kc + 0][row] = b.x; Bs[kc + 1][row] = b.y;
            Bs[kc + 2][row] = b.z; Bs[kc + 3][row] = b.w;
        }
        __syncthreads();

#pragma unroll
        for (int k = 0; k < GEMM_BK; k++) {
            float a[8], b[8];
            *(float4*)&a[0] = *(const float4*)&As[k][ty * 8];
            *(float4*)&a[4] = *(const float4*)&As[k][ty * 8 + 4];
            *(float4*)&b[0] = *(const float4*)&Bs[k][tx * 8];
            *(float4*)&b[4] = *(const float4*)&Bs[k][tx * 8 + 4];
#pragma unroll
            for (int i = 0; i < 8; i++)
#pragma unroll
                for (int j = 0; j < 8; j++)
                    acc[i][j] = fmaf(a[i], b[j], acc[i][j]);
        }
        __syncthreads();
    }

    float bvals[8];
#pragma unroll
    for (int j = 0; j < 8; j++) bvals[j] = bias[colbase + tx * 8 + j];

#pragma unroll
    for (int i = 0; i < 8; i++) {
        int grow = mbase + ty * 8 + i;
        if (grow >= N) break;
#pragma unroll
        for (int j = 0; j < 8; j += 4) {
            float4 o;
            o.x = acc[i][j + 0] + bvals[j + 0];
            o.y = acc[i][j + 1] + bvals[j + 1];
            o.z = acc[i][j + 2] + bvals[j + 2];
            o.w = acc[i][j + 3] + bvals[j + 3];
            *(float4*)&Out[(size_t)grow * 256 + colbase + tx * 8 + j] = o;
        }
    }
}

// ---- CSR build ----
__global__ void count_deg(const int* __restrict__ dst, int* __restrict__ deg, int E) {
    int e = blockIdx.x * 256 + threadIdx.x;
    if (e < E) atomicAdd(&deg[dst[e]], 1);
}

#define SCAN_CHUNK 2048  // 256 threads x 8

__global__ void scan_phase1(const int* __restrict__ deg, int* __restrict__ partials, int N) {
    __shared__ int sdata[256];
    int base = blockIdx.x * SCAN_CHUNK;
    int sum = 0;
#pragma unroll
    for (int i = 0; i < 8; i++) {
        int idx = base + threadIdx.x + i * 256;
        if (idx < N) sum += deg[idx];
    }
    sdata[threadIdx.x] = sum;
    __syncthreads();
    for (int s = 128; s > 0; s >>= 1) {
        if (threadIdx.x < (unsigned)s) sdata[threadIdx.x] += sdata[threadIdx.x + s];
        __syncthreads();
    }
    if (threadIdx.x == 0) partials[blockIdx.x] = sdata[0];
}

__global__ void scan_phase2(int* __restrict__ partials, int nb) {
    if (threadIdx.x == 0 && blockIdx.x == 0) {
        int run = 0;
        for (int i = 0; i < nb; i++) { int v = partials[i]; partials[i] = run; run += v; }
    }
}

__global__ void scan_phase3(const int* __restrict__ deg, const int* __restrict__ partials,
                            int* __restrict__ offsets, int N, int E) {
    __shared__ int sdata[256];
    int base = blockIdx.x * SCAN_CHUNK;
    int vals[8];
    int sum = 0;
#pragma unroll
    for (int i = 0; i < 8; i++) {
        int idx = base + threadIdx.x * 8 + i;
        vals[i] = (idx < N) ? deg[idx] : 0;
        sum += vals[i];
    }
    sdata[threadIdx.x] = sum;
    __syncthreads();
    for (int s = 1; s < 256; s <<= 1) {
        int v = sdata[threadIdx.x];
        int add = (threadIdx.x >= (unsigned)s) ? sdata[threadIdx.x - s] : 0;
        __syncthreads();
        sdata[threadIdx.x] = v + add;
        __syncthreads();
    }
    int excl = (threadIdx.x == 0) ? 0 : sdata[threadIdx.x - 1];
    int run = partials[blockIdx.x] + excl;
#pragma unroll
    for (int i = 0; i < 8; i++) {
        int idx = base + threadIdx.x * 8 + i;
        if (idx < N) offsets[idx] = run;
        run += vals[i];
    }
    if (blockIdx.x == 0 && threadIdx.x == 0) offsets[N] = E;
}

__global__ void scatter_edges(const int* __restrict__ dst, int* __restrict__ cursor,
                              int* __restrict__ esorted, int E) {
    int e = blockIdx.x * 256 + threadIdx.x;
    if (e < E) {
        int pos = atomicAdd(&cursor[dst[e]], 1);
        esorted[pos] = e;
    }
}

// ---- fused score + segment-softmax + aggregation ----
// One wave per dst node. lane l: head = l>>3, dims (l&7)*4 .. +4 -> float4 per lane.
// Single pass: acc = sum_e exp(clip(K[src].Q[n]/scale)) * V[src]; z = sum scores; out = acc/z.
__global__ __launch_bounds__(256) void edge_agg(
    const float4* __restrict__ Q4, const float4* __restrict__ K4, const float4* __restrict__ V4,
    const int* __restrict__ offsets, const int* __restrict__ esorted,
    const int* __restrict__ src, float4* __restrict__ out4, int N)
{
    const int wave = threadIdx.x >> 6;
    const int lane = threadIdx.x & 63;
    const int n = blockIdx.x * 4 + wave;
    if (n >= N) return;

    const float4 q = Q4[(size_t)n * 64 + lane];
    float4 acc = make_float4(0.f, 0.f, 0.f, 0.f);
    float z = 0.f;

    const int beg = offsets[n];
    const int end = offsets[n + 1];
    for (int i = beg; i < end; i++) {
        int e = esorted[i];
        int s = src[e];
        float4 k4 = K4[(size_t)s * 64 + lane];
        float d = k4.x * q.x + k4.y * q.y + k4.z * q.z + k4.w * q.w;
        // reduce over the 8 lanes of this head (sub-lane bits 0..2)
        d += __shfl_xor(d, 1);
        d += __shfl_xor(d, 2);
        d += __shfl_xor(d, 4);
        float t = fminf(5.f, fmaxf(-5.f, d * 0.17677669529663687f));  // 1/sqrt(32)
        float sc = __expf(t);
        z += sc;
        float4 v4 = V4[(size_t)s * 64 + lane];
        acc.x = fmaf(sc, v4.x, acc.x);
        acc.y = fmaf(sc, v4.y, acc.y);
        acc.z = fmaf(sc, v4.z, acc.z);
        acc.w = fmaf(sc, v4.w, acc.w);
    }
    float inv = (z > 0.f) ? 1.f / z : 0.f;
    float4 o;
    o.x = acc.x * inv; o.y = acc.y * inv; o.z = acc.z * inv; o.w = acc.w * inv;
    out4[(size_t)n * 64 + lane] = o;
}

extern "C" void kernel_launch(void* const* d_in, const int* in_sizes, int n_in,
                              void* d_out, int out_size, void* d_ws, size_t ws_size,
                              hipStream_t stream) {
    const float* h  = (const float*)d_in[0];
    const float* Wq = (const float*)d_in[1];
    const float* bq = (const float*)d_in[2];
    const float* Wk = (const float*)d_in[3];
    const float* bk = (const float*)d_in[4];
    const float* Wv = (const float*)d_in[5];
    const float* bv = (const float*)d_in[6];
    const int*   src = (const int*)d_in[7];
    const int*   dst = (const int*)d_in[8];
    float* out = (float*)d_out;

    const int N = in_sizes[0] / 256;  // h is [N, 256]
    const int E = in_sizes[7];

    // workspace carve-up (256B aligned)
    size_t off = 0;
    auto alloc = [&](size_t bytes) {
        void* p = (char*)d_ws + off;
        off += (bytes + 255) & ~(size_t)255;
        return p;
    };
    float* Q = (float*)alloc((size_t)N * 256 * 4);
    float* K = (float*)alloc((size_t)N * 256 * 4);
    float* V = (float*)alloc((size_t)N * 256 * 4);
    int* deg      = (int*)alloc((size_t)N * 4);
    int* offsets  = (int*)alloc((size_t)(N + 1) * 4);
    int* cursor   = (int*)alloc((size_t)N * 4);
    int* partials = (int*)alloc(1024 * 4);
    int* esorted  = (int*)alloc((size_t)E * 4);

    // 1) QKV projections
    dim3 ggrid((N + GEMM_TM - 1) / GEMM_TM, 6);
    qkv_gemm<<<ggrid, 256, 0, stream>>>(h, Wq, bq, Wk, bk, Wv, bv, Q, K, V, N);

    // 2) CSR build: histogram -> scan -> scatter
    hipMemsetAsync(deg, 0, (size_t)N * 4, stream);
    int eblocks = (E + 255) / 256;
    count_deg<<<eblocks, 256, 0, stream>>>(dst, deg, E);

    int nscan = (N + SCAN_CHUNK - 1) / SCAN_CHUNK;
    scan_phase1<<<nscan, 256, 0, stream>>>(deg, partials, N);
    scan_phase2<<<1, 64, 0, stream>>>(partials, nscan);
    scan_phase3<<<nscan, 256, 0, stream>>>(deg, partials, offsets, N, E);

    hipMemcpyAsync(cursor, offsets, (size_t)N * 4, hipMemcpyDeviceToDevice, stream);
    scatter_edges<<<eblocks, 256, 0, stream>>>(dst, cursor, esorted, E);

    // 3) fused score/softmax/aggregate, one wave per dst node
    int ablocks = (N + 3) / 4;
    edge_agg<<<ablocks, 256, 0, stream>>>((const float4*)Q, (const float4*)K, (const float4*)V,
                                          offsets, esorted, src, (float4*)out, N);
}

// Round 2
// 507.960 us; speedup vs baseline: 1.3805x; 1.3805x over previous
//
#include <hip/hip_runtime.h>
#include <hip/hip_bf16.h>

// N=50000 nodes, IN=256, H=8 heads, D=32, HD=256, E=800000 edges (from in_sizes).

typedef __attribute__((ext_vector_type(8))) short short8;
typedef __attribute__((ext_vector_type(4))) float floatx4;

__device__ __forceinline__ void g2l16(const void* g, void* l) {
    __builtin_amdgcn_global_load_lds(
        (const __attribute__((address_space(1))) unsigned int*)g,
        (__attribute__((address_space(3))) unsigned int*)l, 16, 0, 0);
}

// ---- fp32 -> bf16 conversion (vectorized-ish; trivial traffic) ----
__global__ __launch_bounds__(256) void cvt_bf16(const float* __restrict__ src,
                                                unsigned short* __restrict__ dst, int n4) {
    int i = blockIdx.x * 256 + threadIdx.x;
    if (i >= n4) return;
    float4 f = ((const float4*)src)[i];
    __hip_bfloat16 b0 = __float2bfloat16(f.x);
    __hip_bfloat16 b1 = __float2bfloat16(f.y);
    __hip_bfloat16 b2 = __float2bfloat16(f.z);
    __hip_bfloat16 b3 = __float2bfloat16(f.w);
    ushort4 u;
    u.x = *reinterpret_cast<unsigned short*>(&b0);
    u.y = *reinterpret_cast<unsigned short*>(&b1);
    u.z = *reinterpret_cast<unsigned short*>(&b2);
    u.w = *reinterpret_cast<unsigned short*>(&b3);
    ((ushort4*)dst)[i] = u;
}

// ---- bf16 MFMA QKV projection ----
// out[n,j] = sum_k h[n,k]*W[j,k] + b[j];  A = hb [N][256], B = Wb [768][256] (q,k,v stacked)
// grid: (ceil(N/128), 6). Block 256 = 4 waves; each wave a 64x64 tile (4x4 MFMA 16x16x32).
__global__ __launch_bounds__(256) void qkv_gemm_mfma(
    const unsigned short* __restrict__ hb, const unsigned short* __restrict__ Wb,
    const float* __restrict__ bq, const float* __restrict__ bk, const float* __restrict__ bv,
    float* __restrict__ Q, float* __restrict__ K, float* __restrict__ V, int N)
{
    __shared__ unsigned short Ast[128 * 32];
    __shared__ unsigned short Bst[128 * 32];

    const int tid = threadIdx.x;
    const int wave = tid >> 6;
    const int lane = tid & 63;
    const int m = lane & 15;       // input-frag row index / output col index
    const int q = lane >> 4;       // k-chunk / output row quad
    const int wr = wave >> 1, wc = wave & 1;

    const int mbase = blockIdx.x * 128;
    const int mat = blockIdx.y >> 1;                 // 0:Q 1:K 2:V
    const int colbase = (blockIdx.y & 1) * 128;      // col within [0,256)
    const int wrow0 = blockIdx.y * 128;              // row into Wb [768]

    const float* bias = (mat == 0) ? bq : (mat == 1) ? bk : bv;
    float* Out = (mat == 0) ? Q : (mat == 1) ? K : V;

    floatx4 acc[4][4] = {};

    for (int kk = 0; kk < 256; kk += 32) {
        // A-tile: 128 rows x 32 k bf16 = 8 KB = 512x16B; 2 issues/thread
#pragma unroll
        for (int t = 0; t < 2; t++) {
            int f = t * 256 + tid;
            int row = f >> 2, kc = f & 3;
            int grow = mbase + row; if (grow > N - 1) grow = N - 1;  // tail clamp (stores guarded)
            g2l16(hb + (size_t)grow * 256 + kk + kc * 8,
                  Ast + (size_t)(t * 256 + wave * 64) * 8);
        }
        // B-tile
#pragma unroll
        for (int t = 0; t < 2; t++) {
            int f = t * 256 + tid;
            int row = f >> 2, kc = f & 3;
            g2l16(Wb + (size_t)(wrow0 + row) * 256 + kk + kc * 8,
                  Bst + (size_t)(t * 256 + wave * 64) * 8);
        }
        __syncthreads();

        short8 a[4], b[4];
#pragma unroll
        for (int i = 0; i < 4; i++) {
            int r = wr * 64 + i * 16 + m;
            a[i] = *(const short8*)&Ast[r * 32 + q * 8];
        }
#pragma unroll
        for (int j = 0; j < 4; j++) {
            int c = wc * 64 + j * 16 + m;
            b[j] = *(const short8*)&Bst[c * 32 + q * 8];
        }
#pragma unroll
        for (int i = 0; i < 4; i++)
#pragma unroll
            for (int j = 0; j < 4; j++)
                acc[i][j] = __builtin_amdgcn_mfma_f32_16x16x32_bf16(a[i], b[j], acc[i][j], 0, 0, 0);
        __syncthreads();
    }

    float bvj[4];
#pragma unroll
    for (int j = 0; j < 4; j++) bvj[j] = bias[colbase + wc * 64 + j * 16 + m];

    // C/D layout: col = lane&15, row = (lane>>4)*4 + reg  [m89-verified]
#pragma unroll
    for (int i = 0; i < 4; i++) {
#pragma unroll
        for (int r = 0; r < 4; r++) {
            int grow = mbase + wr * 64 + i * 16 + q * 4 + r;
            if (grow < N) {
                float* op = Out + (size_t)grow * 256 + colbase + wc * 64 + m;
#pragma unroll
                for (int j = 0; j < 4; j++)
                    op[j * 16] = acc[i][j][r] + bvj[j];
            }
        }
    }
}

// ---- CSR build ----
__global__ void count_deg(const int* __restrict__ dst, int* __restrict__ deg, int E) {
    int e = blockIdx.x * 256 + threadIdx.x;
    if (e < E) atomicAdd(&deg[dst[e]], 1);
}

#define SCAN_CHUNK 2048

__global__ void scan_phase1(const int* __restrict__ deg, int* __restrict__ partials, int N) {
    __shared__ int sdata[256];
    int base = blockIdx.x * SCAN_CHUNK;
    int sum = 0;
#pragma unroll
    for (int i = 0; i < 8; i++) {
        int idx = base + threadIdx.x + i * 256;
        if (idx < N) sum += deg[idx];
    }
    sdata[threadIdx.x] = sum;
    __syncthreads();
    for (int s = 128; s > 0; s >>= 1) {
        if (threadIdx.x < (unsigned)s) sdata[threadIdx.x] += sdata[threadIdx.x + s];
        __syncthreads();
    }
    if (threadIdx.x == 0) partials[blockIdx.x] = sdata[0];
}

__global__ void scan_phase2(int* __restrict__ partials, int nb) {
    if (threadIdx.x == 0 && blockIdx.x == 0) {
        int run = 0;
        for (int i = 0; i < nb; i++) { int v = partials[i]; partials[i] = run; run += v; }
    }
}

__global__ void scan_phase3(const int* __restrict__ deg, const int* __restrict__ partials,
                            int* __restrict__ offsets, int N, int E) {
    __shared__ int sdata[256];
    int base = blockIdx.x * SCAN_CHUNK;
    int vals[8];
    int sum = 0;
#pragma unroll
    for (int i = 0; i < 8; i++) {
        int idx = base + threadIdx.x * 8 + i;
        vals[i] = (idx < N) ? deg[idx] : 0;
        sum += vals[i];
    }
    sdata[threadIdx.x] = sum;
    __syncthreads();
    for (int s = 1; s < 256; s <<= 1) {
        int v = sdata[threadIdx.x];
        int add = (threadIdx.x >= (unsigned)s) ? sdata[threadIdx.x - s] : 0;
        __syncthreads();
        sdata[threadIdx.x] = v + add;
        __syncthreads();
    }
    int excl = (threadIdx.x == 0) ? 0 : sdata[threadIdx.x - 1];
    int run = partials[blockIdx.x] + excl;
#pragma unroll
    for (int i = 0; i < 8; i++) {
        int idx = base + threadIdx.x * 8 + i;
        if (idx < N) offsets[idx] = run;
        run += vals[i];
    }
    if (blockIdx.x == 0 && threadIdx.x == 0) offsets[N] = E;
}

// store SOURCE NODE id (not edge id) -> removes one indirection in edge_agg
__global__ void scatter_edges(const int* __restrict__ dst, const int* __restrict__ src,
                              int* __restrict__ cursor, int* __restrict__ ssorted, int E) {
    int e = blockIdx.x * 256 + threadIdx.x;
    if (e < E) {
        int pos = atomicAdd(&cursor[dst[e]], 1);
        ssorted[pos] = src[e];
    }
}

// ---- fused score + segment-softmax + aggregation, one wave per dst node ----
__global__ __launch_bounds__(256) void edge_agg(
    const float4* __restrict__ Q4, const float4* __restrict__ K4, const float4* __restrict__ V4,
    const int* __restrict__ offsets, const int* __restrict__ ssorted,
    float4* __restrict__ out4, int N)
{
    const int wave = threadIdx.x >> 6;
    const int lane = threadIdx.x & 63;
    const int n = blockIdx.x * 4 + wave;
    if (n >= N) return;

    const float4 qv = Q4[(size_t)n * 64 + lane];
    float4 acc = make_float4(0.f, 0.f, 0.f, 0.f);
    float z = 0.f;

    const int beg = offsets[n];
    const int end = offsets[n + 1];
    const float scale = 0.17677669529663687f;  // 1/sqrt(32)

    int i = beg;
    int s0 = (beg < end) ? ssorted[beg] : 0;
    // unroll x2 with prefetch: 4 KB of gathers in flight per wave
    for (; i + 1 < end; i += 2) {
        int s1 = ssorted[i + 1];
        float4 k0 = K4[(size_t)s0 * 64 + lane];
        float4 v0 = V4[(size_t)s0 * 64 + lane];
        float4 k1 = K4[(size_t)s1 * 64 + lane];
        float4 v1 = V4[(size_t)s1 * 64 + lane];
        int snext = (i + 2 < end) ? ssorted[i + 2] : 0;

        float d0 = fmaf(k0.x, qv.x, fmaf(k0.y, qv.y, fmaf(k0.z, qv.z, k0.w * qv.w)));
        d0 += __shfl_xor(d0, 1); d0 += __shfl_xor(d0, 2); d0 += __shfl_xor(d0, 4);
        float t0 = fminf(5.f, fmaxf(-5.f, d0 * scale));
        float sc0 = __expf(t0);
        z += sc0;
        acc.x = fmaf(sc0, v0.x, acc.x); acc.y = fmaf(sc0, v0.y, acc.y);
        acc.z = fmaf(sc0, v0.z, acc.z); acc.w = fmaf(sc0, v0.w, acc.w);

        float d1 = fmaf(k1.x, qv.x, fmaf(k1.y, qv.y, fmaf(k1.z, qv.z, k1.w * qv.w)));
        d1 += __shfl_xor(d1, 1); d1 += __shfl_xor(d1, 2); d1 += __shfl_xor(d1, 4);
        float t1 = fminf(5.f, fmaxf(-5.f, d1 * scale));
        float sc1 = __expf(t1);
        z += sc1;
        acc.x = fmaf(sc1, v1.x, acc.x); acc.y = fmaf(sc1, v1.y, acc.y);
        acc.z = fmaf(sc1, v1.z, acc.z); acc.w = fmaf(sc1, v1.w, acc.w);

        s0 = snext;
    }
    if (i < end) {
        float4 k0 = K4[(size_t)s0 * 64 + lane];
        float4 v0 = V4[(size_t)s0 * 64 + lane];
        float d0 = fmaf(k0.x, qv.x, fmaf(k0.y, qv.y, fmaf(k0.z, qv.z, k0.w * qv.w)));
        d0 += __shfl_xor(d0, 1); d0 += __shfl_xor(d0, 2); d0 += __shfl_xor(d0, 4);
        float t0 = fminf(5.f, fmaxf(-5.f, d0 * scale));
        float sc0 = __expf(t0);
        z += sc0;
        acc.x = fmaf(sc0, v0.x, acc.x); acc.y = fmaf(sc0, v0.y, acc.y);
        acc.z = fmaf(sc0, v0.z, acc.z); acc.w = fmaf(sc0, v0.w, acc.w);
    }

    float inv = (z > 0.f) ? 1.f / z : 0.f;
    out4[(size_t)n * 64 + lane] = make_float4(acc.x * inv, acc.y * inv, acc.z * inv, acc.w * inv);
}

extern "C" void kernel_launch(void* const* d_in, const int* in_sizes, int n_in,
                              void* d_out, int out_size, void* d_ws, size_t ws_size,
                              hipStream_t stream) {
    const float* h  = (const float*)d_in[0];
    const float* Wq = (const float*)d_in[1];
    const float* bq = (const float*)d_in[2];
    const float* Wk = (const float*)d_in[3];
    const float* bk = (const float*)d_in[4];
    const float* Wv = (const float*)d_in[5];
    const float* bv = (const float*)d_in[6];
    const int*   src = (const int*)d_in[7];
    const int*   dst = (const int*)d_in[8];
    float* out = (float*)d_out;

    const int N = in_sizes[0] / 256;
    const int E = in_sizes[7];

    size_t off = 0;
    auto alloc = [&](size_t bytes) {
        void* p = (char*)d_ws + off;
        off += (bytes + 255) & ~(size_t)255;
        return p;
    };
    float* Q = (float*)alloc((size_t)N * 256 * 4);
    float* K = (float*)alloc((size_t)N * 256 * 4);
    float* V = (float*)alloc((size_t)N * 256 * 4);
    unsigned short* hb = (unsigned short*)alloc((size_t)N * 256 * 2);
    unsigned short* Wb = (unsigned short*)alloc((size_t)768 * 256 * 2);
    int* deg      = (int*)alloc((size_t)N * 4);
    int* offsets  = (int*)alloc((size_t)(N + 1) * 4);
    int* cursor   = (int*)alloc((size_t)N * 4);
    int* partials = (int*)alloc(1024 * 4);
    int* ssorted  = (int*)alloc((size_t)E * 4);

    // 0) bf16 conversions
    int n4h = (N * 256) / 4;
    cvt_bf16<<<(n4h + 255) / 256, 256, 0, stream>>>(h, hb, n4h);
    int n4w = (256 * 256) / 4;
    cvt_bf16<<<(n4w + 255) / 256, 256, 0, stream>>>(Wq, Wb, n4w);
    cvt_bf16<<<(n4w + 255) / 256, 256, 0, stream>>>(Wk, Wb + 256 * 256, n4w);
    cvt_bf16<<<(n4w + 255) / 256, 256, 0, stream>>>(Wv, Wb + 2 * 256 * 256, n4w);

    // 1) QKV projections (bf16 MFMA)
    dim3 ggrid((N + 127) / 128, 6);
    qkv_gemm_mfma<<<ggrid, 256, 0, stream>>>(hb, Wb, bq, bk, bv, Q, K, V, N);

    // 2) CSR build
    hipMemsetAsync(deg, 0, (size_t)N * 4, stream);
    int eblocks = (E + 255) / 256;
    count_deg<<<eblocks, 256, 0, stream>>>(dst, deg, E);

    int nscan = (N + SCAN_CHUNK - 1) / SCAN_CHUNK;
    scan_phase1<<<nscan, 256, 0, stream>>>(deg, partials, N);
    scan_phase2<<<1, 64, 0, stream>>>(partials, nscan);
    scan_phase3<<<nscan, 256, 0, stream>>>(deg, partials, offsets, N, E);

    hipMemcpyAsync(cursor, offsets, (size_t)N * 4, hipMemcpyDeviceToDevice, stream);
    scatter_edges<<<eblocks, 256, 0, stream>>>(dst, src, cursor, ssorted, E);

    // 3) fused score/softmax/aggregate
    int ablocks = (N + 3) / 4;
    edge_agg<<<ablocks, 256, 0, stream>>>((const float4*)Q, (const float4*)K, (const float4*)V,
                                          offsets, ssorted, (float4*)out, N);
}

// Round 3
// 391.742 us; speedup vs baseline: 1.7901x; 1.2967x over previous
//
#include <hip/hip_runtime.h>
#include <hip/hip_bf16.h>

// N=50000 nodes, IN=256, H=8 heads, D=32, HD=256, E=800000 edges (from in_sizes).

typedef __attribute__((ext_vector_type(8))) short short8;
typedef __attribute__((ext_vector_type(8))) unsigned short ushortx8;
typedef __attribute__((ext_vector_type(4))) float floatx4;

__device__ __forceinline__ void g2l16(const void* g, void* l) {
    __builtin_amdgcn_global_load_lds(
        (const __attribute__((address_space(1))) unsigned int*)g,
        (__attribute__((address_space(3))) unsigned int*)l, 16, 0, 0);
}

__device__ __forceinline__ float bf2f(unsigned short u) {
    union { unsigned int i; float f; } c; c.i = ((unsigned int)u) << 16; return c.f;
}
__device__ __forceinline__ unsigned short f2bf(float f) {
    __hip_bfloat16 b = __float2bfloat16(f);
    return *reinterpret_cast<unsigned short*>(&b);
}

// ---- fp32 -> bf16 conversion ----
__global__ __launch_bounds__(256) void cvt_bf16(const float* __restrict__ src,
                                                unsigned short* __restrict__ dst, int n4) {
    int i = blockIdx.x * 256 + threadIdx.x;
    if (i >= n4) return;
    float4 f = ((const float4*)src)[i];
    ushort4 u;
    u.x = f2bf(f.x); u.y = f2bf(f.y); u.z = f2bf(f.z); u.w = f2bf(f.w);
    ((ushort4*)dst)[i] = u;
}

// ---- bf16 MFMA QKV projection ----
// A = hb [N][256], B = Wb [768][256] (q,k,v stacked).
// Q written fp32; K,V written bf16 (halves edge_agg gather traffic).
// grid: (ceil(N/128), 6). Block 256 = 4 waves; each wave 64x64 (4x4 MFMA 16x16x32).
__global__ __launch_bounds__(256) void qkv_gemm_mfma(
    const unsigned short* __restrict__ hb, const unsigned short* __restrict__ Wb,
    const float* __restrict__ bq, const float* __restrict__ bk, const float* __restrict__ bv,
    float* __restrict__ Q, unsigned short* __restrict__ Kb, unsigned short* __restrict__ Vb,
    int N)
{
    __shared__ unsigned short Ast[128 * 32];
    __shared__ unsigned short Bst[128 * 32];

    const int tid = threadIdx.x;
    const int wave = tid >> 6;
    const int lane = tid & 63;
    const int m = lane & 15;
    const int q = lane >> 4;
    const int wr = wave >> 1, wc = wave & 1;

    const int mbase = blockIdx.x * 128;
    const int mat = blockIdx.y >> 1;                 // 0:Q 1:K 2:V
    const int colbase = (blockIdx.y & 1) * 128;
    const int wrow0 = blockIdx.y * 128;

    const float* bias = (mat == 0) ? bq : (mat == 1) ? bk : bv;

    floatx4 acc[4][4] = {};

    for (int kk = 0; kk < 256; kk += 32) {
#pragma unroll
        for (int t = 0; t < 2; t++) {
            int f = t * 256 + tid;
            int row = f >> 2, kc = f & 3;
            int grow = mbase + row; if (grow > N - 1) grow = N - 1;
            g2l16(hb + (size_t)grow * 256 + kk + kc * 8,
                  Ast + (size_t)(t * 256 + wave * 64) * 8);
        }
#pragma unroll
        for (int t = 0; t < 2; t++) {
            int f = t * 256 + tid;
            int row = f >> 2, kc = f & 3;
            g2l16(Wb + (size_t)(wrow0 + row) * 256 + kk + kc * 8,
                  Bst + (size_t)(t * 256 + wave * 64) * 8);
        }
        __syncthreads();

        short8 a[4], b[4];
#pragma unroll
        for (int i = 0; i < 4; i++) {
            int r = wr * 64 + i * 16 + m;
            a[i] = *(const short8*)&Ast[r * 32 + q * 8];
        }
#pragma unroll
        for (int j = 0; j < 4; j++) {
            int c = wc * 64 + j * 16 + m;
            b[j] = *(const short8*)&Bst[c * 32 + q * 8];
        }
#pragma unroll
        for (int i = 0; i < 4; i++)
#pragma unroll
            for (int j = 0; j < 4; j++)
                acc[i][j] = __builtin_amdgcn_mfma_f32_16x16x32_bf16(a[i], b[j], acc[i][j], 0, 0, 0);
        __syncthreads();
    }

    float bvj[4];
#pragma unroll
    for (int j = 0; j < 4; j++) bvj[j] = bias[colbase + wc * 64 + j * 16 + m];

    // C/D layout: col = lane&15, row = (lane>>4)*4 + reg
#pragma unroll
    for (int i = 0; i < 4; i++) {
#pragma unroll
        for (int r = 0; r < 4; r++) {
            int grow = mbase + wr * 64 + i * 16 + q * 4 + r;
            if (grow < N) {
                size_t base = (size_t)grow * 256 + colbase + wc * 64 + m;
                if (mat == 0) {
                    float* op = Q + base;
#pragma unroll
                    for (int j = 0; j < 4; j++) op[j * 16] = acc[i][j][r] + bvj[j];
                } else {
                    unsigned short* op = ((mat == 1) ? Kb : Vb) + base;
#pragma unroll
                    for (int j = 0; j < 4; j++) op[j * 16] = f2bf(acc[i][j][r] + bvj[j]);
                }
            }
        }
    }
}

// ---- CSR build ----
__global__ void count_deg(const int* __restrict__ dst, int* __restrict__ deg, int E) {
    int e = blockIdx.x * 256 + threadIdx.x;
    if (e < E) atomicAdd(&deg[dst[e]], 1);
}

#define SCAN_CHUNK 2048

__global__ void scan_phase1(const int* __restrict__ deg, int* __restrict__ partials, int N) {
    __shared__ int sdata[256];
    int base = blockIdx.x * SCAN_CHUNK;
    int sum = 0;
#pragma unroll
    for (int i = 0; i < 8; i++) {
        int idx = base + threadIdx.x + i * 256;
        if (idx < N) sum += deg[idx];
    }
    sdata[threadIdx.x] = sum;
    __syncthreads();
    for (int s = 128; s > 0; s >>= 1) {
        if (threadIdx.x < (unsigned)s) sdata[threadIdx.x] += sdata[threadIdx.x + s];
        __syncthreads();
    }
    if (threadIdx.x == 0) partials[blockIdx.x] = sdata[0];
}

__global__ void scan_phase2(int* __restrict__ partials, int nb) {
    if (threadIdx.x == 0 && blockIdx.x == 0) {
        int run = 0;
        for (int i = 0; i < nb; i++) { int v = partials[i]; partials[i] = run; run += v; }
    }
}

__global__ void scan_phase3(const int* __restrict__ deg, const int* __restrict__ partials,
                            int* __restrict__ offsets, int N, int E) {
    __shared__ int sdata[256];
    int base = blockIdx.x * SCAN_CHUNK;
    int vals[8];
    int sum = 0;
#pragma unroll
    for (int i = 0; i < 8; i++) {
        int idx = base + threadIdx.x * 8 + i;
        vals[i] = (idx < N) ? deg[idx] : 0;
        sum += vals[i];
    }
    sdata[threadIdx.x] = sum;
    __syncthreads();
    for (int s = 1; s < 256; s <<= 1) {
        int v = sdata[threadIdx.x];
        int add = (threadIdx.x >= (unsigned)s) ? sdata[threadIdx.x - s] : 0;
        __syncthreads();
        sdata[threadIdx.x] = v + add;
        __syncthreads();
    }
    int excl = (threadIdx.x == 0) ? 0 : sdata[threadIdx.x - 1];
    int run = partials[blockIdx.x] + excl;
#pragma unroll
    for (int i = 0; i < 8; i++) {
        int idx = base + threadIdx.x * 8 + i;
        if (idx < N) offsets[idx] = run;
        run += vals[i];
    }
    if (blockIdx.x == 0 && threadIdx.x == 0) offsets[N] = E;
}

__global__ void scatter_edges(const int* __restrict__ dst, const int* __restrict__ src,
                              int* __restrict__ cursor, int* __restrict__ ssorted, int E) {
    int e = blockIdx.x * 256 + threadIdx.x;
    if (e < E) {
        int pos = atomicAdd(&cursor[dst[e]], 1);
        ssorted[pos] = src[e];
    }
}

// ---- fused score + segment-softmax + aggregation ----
// One wave per dst node, TWO edges in flight (one per 32-lane half), unrolled x2.
// Half-lane hl holds dims hl*8..hl*8+8 (bf16x8 = 16B); head = hl>>2 (4 lanes/head).
__global__ __launch_bounds__(256) void edge_agg(
    const float4* __restrict__ Q4, const unsigned short* __restrict__ Kb,
    const unsigned short* __restrict__ Vb,
    const int* __restrict__ offsets, const int* __restrict__ ssorted,
    float4* __restrict__ out4, int N)
{
    const int wave = threadIdx.x >> 6;
    const int lane = threadIdx.x & 63;
    const int half = lane >> 5;
    const int hl = lane & 31;
    const int n = blockIdx.x * 4 + wave;
    if (n >= N) return;

    float q[8];
    *(float4*)&q[0] = Q4[(size_t)n * 64 + hl * 2];
    *(float4*)&q[4] = Q4[(size_t)n * 64 + hl * 2 + 1];

    float acc[8] = {};
    float z = 0.f;
    const int beg = offsets[n], end = offsets[n + 1];
    const float scale = 0.17677669529663687f;  // 1/sqrt(32)

    int i = beg + half;
    for (; i + 2 < end; i += 4) {
        int sa = ssorted[i];
        int sb = ssorted[i + 2];
        ushortx8 ka = *(const ushortx8*)&Kb[(size_t)sa * 256 + hl * 8];
        ushortx8 va = *(const ushortx8*)&Vb[(size_t)sa * 256 + hl * 8];
        ushortx8 kb = *(const ushortx8*)&Kb[(size_t)sb * 256 + hl * 8];
        ushortx8 vb = *(const ushortx8*)&Vb[(size_t)sb * 256 + hl * 8];

        float da = 0.f;
#pragma unroll
        for (int j = 0; j < 8; j++) da = fmaf(bf2f(ka[j]), q[j], da);
        da += __shfl_xor(da, 1); da += __shfl_xor(da, 2);
        float sca = __expf(fminf(5.f, fmaxf(-5.f, da * scale)));
        z += sca;
#pragma unroll
        for (int j = 0; j < 8; j++) acc[j] = fmaf(sca, bf2f(va[j]), acc[j]);

        float db = 0.f;
#pragma unroll
        for (int j = 0; j < 8; j++) db = fmaf(bf2f(kb[j]), q[j], db);
        db += __shfl_xor(db, 1); db += __shfl_xor(db, 2);
        float scb = __expf(fminf(5.f, fmaxf(-5.f, db * scale)));
        z += scb;
#pragma unroll
        for (int j = 0; j < 8; j++) acc[j] = fmaf(scb, bf2f(vb[j]), acc[j]);
    }
    for (; i < end; i += 2) {
        int s = ssorted[i];
        ushortx8 k8 = *(const ushortx8*)&Kb[(size_t)s * 256 + hl * 8];
        ushortx8 v8 = *(const ushortx8*)&Vb[(size_t)s * 256 + hl * 8];
        float d = 0.f;
#pragma unroll
        for (int j = 0; j < 8; j++) d = fmaf(bf2f(k8[j]), q[j], d);
        d += __shfl_xor(d, 1); d += __shfl_xor(d, 2);
        float sc = __expf(fminf(5.f, fmaxf(-5.f, d * scale)));
        z += sc;
#pragma unroll
        for (int j = 0; j < 8; j++) acc[j] = fmaf(sc, bf2f(v8[j]), acc[j]);
    }

    // combine the two halves
    z += __shfl_xor(z, 32);
#pragma unroll
    for (int j = 0; j < 8; j++) acc[j] += __shfl_xor(acc[j], 32);

    if (half == 0) {
        float inv = (z > 0.f) ? 1.f / z : 0.f;
        float4 o0, o1;
        o0.x = acc[0] * inv; o0.y = acc[1] * inv; o0.z = acc[2] * inv; o0.w = acc[3] * inv;
        o1.x = acc[4] * inv; o1.y = acc[5] * inv; o1.z = acc[6] * inv; o1.w = acc[7] * inv;
        out4[(size_t)n * 64 + hl * 2]     = o0;
        out4[(size_t)n * 64 + hl * 2 + 1] = o1;
    }
}

extern "C" void kernel_launch(void* const* d_in, const int* in_sizes, int n_in,
                              void* d_out, int out_size, void* d_ws, size_t ws_size,
                              hipStream_t stream) {
    const float* h  = (const float*)d_in[0];
    const float* Wq = (const float*)d_in[1];
    const float* bq = (const float*)d_in[2];
    const float* Wk = (const float*)d_in[3];
    const float* bk = (const float*)d_in[4];
    const float* Wv = (const float*)d_in[5];
    const float* bv = (const float*)d_in[6];
    const int*   src = (const int*)d_in[7];
    const int*   dst = (const int*)d_in[8];
    float* out = (float*)d_out;

    const int N = in_sizes[0] / 256;
    const int E = in_sizes[7];

    size_t off = 0;
    auto alloc = [&](size_t bytes) {
        void* p = (char*)d_ws + off;
        off += (bytes + 255) & ~(size_t)255;
        return p;
    };
    float* Q           = (float*)alloc((size_t)N * 256 * 4);
    unsigned short* Kb = (unsigned short*)alloc((size_t)N * 256 * 2);
    unsigned short* Vb = (unsigned short*)alloc((size_t)N * 256 * 2);
    unsigned short* hb = (unsigned short*)alloc((size_t)N * 256 * 2);
    unsigned short* Wb = (unsigned short*)alloc((size_t)768 * 256 * 2);
    int* deg      = (int*)alloc((size_t)N * 4);
    int* offsets  = (int*)alloc((size_t)(N + 1) * 4);
    int* cursor   = (int*)alloc((size_t)N * 4);
    int* partials = (int*)alloc(1024 * 4);
    int* ssorted  = (int*)alloc((size_t)E * 4);

    // 0) bf16 conversions
    int n4h = (N * 256) / 4;
    cvt_bf16<<<(n4h + 255) / 256, 256, 0, stream>>>(h, hb, n4h);
    int n4w = (256 * 256) / 4;
    cvt_bf16<<<(n4w + 255) / 256, 256, 0, stream>>>(Wq, Wb, n4w);
    cvt_bf16<<<(n4w + 255) / 256, 256, 0, stream>>>(Wk, Wb + 256 * 256, n4w);
    cvt_bf16<<<(n4w + 255) / 256, 256, 0, stream>>>(Wv, Wb + 2 * 256 * 256, n4w);

    // 1) QKV projections (bf16 MFMA; K,V stored bf16)
    dim3 ggrid((N + 127) / 128, 6);
    qkv_gemm_mfma<<<ggrid, 256, 0, stream>>>(hb, Wb, bq, bk, bv, Q, Kb, Vb, N);

    // 2) CSR build
    hipMemsetAsync(deg, 0, (size_t)N * 4, stream);
    int eblocks = (E + 255) / 256;
    count_deg<<<eblocks, 256, 0, stream>>>(dst, deg, E);

    int nscan = (N + SCAN_CHUNK - 1) / SCAN_CHUNK;
    scan_phase1<<<nscan, 256, 0, stream>>>(deg, partials, N);
    scan_phase2<<<1, 64, 0, stream>>>(partials, nscan);
    scan_phase3<<<nscan, 256, 0, stream>>>(deg, partials, offsets, N, E);

    hipMemcpyAsync(cursor, offsets, (size_t)N * 4, hipMemcpyDeviceToDevice, stream);
    scatter_edges<<<eblocks, 256, 0, stream>>>(dst, src, cursor, ssorted, E);

    // 3) fused score/softmax/aggregate
    int ablocks = (N + 3) / 4;
    edge_agg<<<ablocks, 256, 0, stream>>>((const float4*)Q, Kb, Vb,
                                          offsets, ssorted, (float4*)out, N);
}